// Round 13
// baseline (712.296 us; speedup 1.0000x reference)
//
#include <hip/hip_runtime.h>

// AutoregressiveForecaster R13: R9 base + Pade-7/6 tanh (trans 7->5 per gate-step).
// 2-layer LSTM(H=64) + MLP head, 20 autoregressive steps, 24-window, B=8192.
//
//  - 512 blocks x 256 threads (4 waves), block owns one 16-batch MFMA M-tile,
//    2 blocks/CU (launch_bounds(256,2); arg2 = min blocks/CU per R6/R7).
//  - Wave w owns gate-tiles {w,w+4,w+8,w+12} = gates i,f,g,o of units
//    [16w,16w+16): elementwise lane-local, c-state in registers.
//  - Pipelined: iter t computes L1(t) [K=128] + L0(t+1) [K=64], ping-pong
//    staging, 1 __syncthreads/iter (R9 structure; R12's folding regressed).
//  - TRANS DIET: VALUBusy pinned ~67% across R4/R9/R12 = trans unit at
//    16cy/wave64-instr (56 trans x 2 waves x 16 = 1792 of 2655 cy/interval).
//    Both tanhs -> clamped Pade-7/6 on the regular VALU; denominators folded
//    into the existing rcps: 3 exp2 + 2 rcp per unit-step (was 5+2).
//  - Weight scales: i,f,o rows pre-scaled by log2e (exp2 path); g rows RAW
//    (Pade path). Cell c stays in real units (tanh(c) via Pade).
//  - Pade err <=1.5e-5 for |x|<=4, <=1e-4 clamped at +-5 (tanh(5)=0.99991).

typedef _Float16 f16x8 __attribute__((ext_vector_type(8)));
typedef float f32x4 __attribute__((ext_vector_type(4)));

#define NBLK 512
#define NTHR 256
#define SRB  144   // h row stride bytes

__device__ __forceinline__ float rcp_(float x) { return __builtin_amdgcn_rcpf(x); }
__device__ __forceinline__ float exp2_(float x) { return __builtin_amdgcn_exp2f(x); }
__device__ __forceinline__ f32x4 mfma16(uint4 a, uint4 b, f32x4 c) {
  return __builtin_amdgcn_mfma_f32_16x16x32_f16(
      __builtin_bit_cast(f16x8, a), __builtin_bit_cast(f16x8, b), c, 0, 0, 0);
}
__device__ __forceinline__ uint4 pack8s(const float* p, float s) {
  union { uint4 u; _Float16 h[8]; } r;
  #pragma unroll
  for (int i = 0; i < 8; ++i) r.h[i] = (_Float16)(p[i] * s);
  return r.u;
}
// fused LSTM gate update. aI,aF,aO pre-scaled by log2e; aG RAW; c in real units.
// sigm via exp2+shared rcp; both tanhs via Pade-7/6 with denominators folded
// into the two rcps. 3 exp2 + 2 rcp + ~20 VALU.
__device__ __forceinline__ float gatestep(float aI, float aF, float aG, float aO,
                                          float& cst) {
  float xx = exp2_(-aI), xf = exp2_(-aF), xo = exp2_(-aO);
  float tg = fminf(fmaxf(aG, -5.0f), 5.0f);
  float g2 = tg * tg;
  float ng = tg * fmaf(g2, fmaf(g2, fmaf(g2, 1.0f, 378.0f), 17325.0f), 135135.0f);
  float dg = fmaf(g2, fmaf(g2, fmaf(g2, 28.0f, 3150.0f), 62370.0f), 135135.0f);
  float pxx = 1.0f + xx, pxf = 1.0f + xf;
  float N = fmaf(cst * pxx, dg, ng * pxf);       // c*(1+xx)*dg + ng*(1+xf)
  float cv = N * rcp_(pxf * pxx * dg);
  cst = cv;
  float tc = fminf(fmaxf(cv, -5.0f), 5.0f);
  float c2 = tc * tc;
  float nc = tc * fmaf(c2, fmaf(c2, fmaf(c2, 1.0f, 378.0f), 17325.0f), 135135.0f);
  float dc = fmaf(c2, fmaf(c2, fmaf(c2, 28.0f, 3150.0f), 62370.0f), 135135.0f);
  return nc * rcp_((1.0f + xo) * dc);
}

__global__ __launch_bounds__(NTHR, 2) void lstm_forecast(
    const float* __restrict__ x,
    const float* __restrict__ Wih0, const float* __restrict__ Whh0,
    const float* __restrict__ bih0, const float* __restrict__ bhh0,
    const float* __restrict__ Wih1, const float* __restrict__ Whh1,
    const float* __restrict__ bih1, const float* __restrict__ bhh1,
    const float* __restrict__ W1,   const float* __restrict__ b1,
    const float* __restrict__ W2,   const float* __restrict__ b2,
    const float* __restrict__ damping, const int* __restrict__ stepsPtr,
    float* __restrict__ out)
{
  __shared__ __align__(16) char h1s[2][16 * SRB];
  __shared__ __align__(16) char h2s[2][16 * SRB];
  __shared__ __align__(16) float win[24 * 16];
  __shared__ __align__(16) float pm[2][16];

  const int tid  = threadIdx.x;
  const int wave = tid >> 6;
  const int lane = tid & 63;
  const int cc   = lane & 15;
  const int hi   = lane >> 4;
  const int b0g  = blockIdx.x * 16;
  const float L2E = 1.44269504089f;

  // ---- weight B-fragments into VGPRs (i,f,o scaled by log2e; g RAW) ----
  uint4 wB0[4][2], wB1[4][2], wB2[4][2];
  float bias0v[4], wih0v[4];
  f32x4 bi1[4];
  #pragma unroll
  for (int gt = 0; gt < 4; ++gt) {
    float sc = (gt == 2) ? 1.0f : L2E;
    int row = (wave + 4 * gt) * 16 + cc;
    #pragma unroll
    for (int f = 0; f < 2; ++f) {
      int col = f * 32 + hi * 8;
      wB0[gt][f] = pack8s(Whh0 + row * 64 + col, sc);
      wB1[gt][f] = pack8s(Wih1 + row * 64 + col, sc);
      wB2[gt][f] = pack8s(Whh1 + row * 64 + col, sc);
    }
    bias0v[gt] = (bih0[row] + bhh0[row]) * sc;
    wih0v[gt]  = Wih0[row] * sc;
    float b1c  = (bih1[row] + bhh1[row]) * sc;
    #pragma unroll
    for (int r = 0; r < 4; ++r) bi1[gt][r] = b1c;
  }
  // MLP fragments (waves 0,1 use them; 2,3 load duplicates harmlessly)
  uint4 wM[2];
  {
    int row = (wave & 1) * 16 + cc;
    wM[0] = pack8s(W1 + row * 64 + hi * 8, 1.0f);
    wM[1] = pack8s(W1 + row * 64 + 32 + hi * 8, 1.0f);
  }
  const float w2v  = W2[(wave & 1) * 16 + cc];
  const float b1vv = b1[(wave & 1) * 16 + cc];
  const float alpha  = rcp_(1.0f + exp2_(-L2E * damping[0]));
  const int   nsteps = stepsPtr[0];
  const float b2v    = b2[0];

  // window init: win[t*16+b] = x[(b0g+b)*24 + t]
  for (int e = tid; e < 384; e += NTHR) {
    int b = e & 15, t = e >> 4;
    win[t * 16 + b] = x[(b0g + b) * 24 + t];
  }
  __syncthreads();

  const int offA = cc * SRB + hi * 16;           // A-frag byte offset
  const int offS = (wave * 16 + cc) * 2;         // elementwise store offset
  float prevp = 0.0f;

  for (int s = 0; s < nsteps; ++s) {
    float c1[4] = {0, 0, 0, 0}, c2s[4] = {0, 0, 0, 0};

    // ---- prologue: L0(0) elementwise only (h1(-1)=0) -> h1s[0] ----
    {
      float4 xw = *(const float4*)&win[(s % 24) * 16 + hi * 4];
      float xa[4] = {xw.x, xw.y, xw.z, xw.w};
      #pragma unroll
      for (int r = 0; r < 4; ++r) {
        float hv = gatestep(fmaf(xa[r], wih0v[0], bias0v[0]),
                            fmaf(xa[r], wih0v[1], bias0v[1]),
                            fmaf(xa[r], wih0v[2], bias0v[2]),
                            fmaf(xa[r], wih0v[3], bias0v[3]), c1[r]);
        *(_Float16*)(h1s[0] + (hi * 4 + r) * SRB + offS) = (_Float16)hv;
      }
    }
    __syncthreads();
    uint4 a1lo = *(const uint4*)(h1s[0] + offA);
    uint4 a1hi = *(const uint4*)(h1s[0] + offA + 64);
    uint4 a2lo = make_uint4(0, 0, 0, 0), a2hi = make_uint4(0, 0, 0, 0);

    // ---- main pipelined loop: iter t computes L1(t) and L0(t+1) ----
    for (int t = 0; t < 23; ++t) {
      int pb = (t + 1) & 1;
      int ph = s + t + 1; if (ph >= 24) ph -= 24;
      float4 xw = *(const float4*)&win[ph * 16 + hi * 4];
      float xa[4] = {xw.x, xw.y, xw.z, xw.w};

      f32x4 acc1[4], acc0[4];
      #pragma unroll
      for (int gt = 0; gt < 4; ++gt) {
        f32x4 tv = mfma16(a1lo, wB1[gt][0], bi1[gt]);
        tv = mfma16(a1hi, wB1[gt][1], tv);
        tv = mfma16(a2lo, wB2[gt][0], tv);
        acc1[gt] = mfma16(a2hi, wB2[gt][1], tv);
      }
      #pragma unroll
      for (int gt = 0; gt < 4; ++gt) {
        f32x4 ai;
        #pragma unroll
        for (int r = 0; r < 4; ++r) ai[r] = fmaf(xa[r], wih0v[gt], bias0v[gt]);
        f32x4 tv = mfma16(a1lo, wB0[gt][0], ai);
        acc0[gt] = mfma16(a1hi, wB0[gt][1], tv);
      }

      char* h2d = h2s[pb];
      char* h1d = h1s[pb];
      #pragma unroll
      for (int r = 0; r < 4; ++r) {
        float hv = gatestep(acc1[0][r], acc1[1][r], acc1[2][r], acc1[3][r], c2s[r]);
        *(_Float16*)(h2d + (hi * 4 + r) * SRB + offS) = (_Float16)hv;
      }
      #pragma unroll
      for (int r = 0; r < 4; ++r) {
        float hv = gatestep(acc0[0][r], acc0[1][r], acc0[2][r], acc0[3][r], c1[r]);
        *(_Float16*)(h1d + (hi * 4 + r) * SRB + offS) = (_Float16)hv;
      }
      __syncthreads();
      a1lo = *(const uint4*)(h1s[pb] + offA);
      a1hi = *(const uint4*)(h1s[pb] + offA + 64);
      a2lo = *(const uint4*)(h2s[pb] + offA);
      a2hi = *(const uint4*)(h2s[pb] + offA + 64);
    } // t

    // ---- epilogue: L1(23) -> h2s[0] ----
    {
      f32x4 acc1[4];
      #pragma unroll
      for (int gt = 0; gt < 4; ++gt) {
        f32x4 tv = mfma16(a1lo, wB1[gt][0], bi1[gt]);
        tv = mfma16(a1hi, wB1[gt][1], tv);
        tv = mfma16(a2lo, wB2[gt][0], tv);
        acc1[gt] = mfma16(a2hi, wB2[gt][1], tv);
      }
      #pragma unroll
      for (int r = 0; r < 4; ++r) {
        float cv = c2s[r];
        float hv = gatestep(acc1[0][r], acc1[1][r], acc1[2][r], acc1[3][r], cv);
        *(_Float16*)(h2s[0] + (hi * 4 + r) * SRB + offS) = (_Float16)hv;
      }
    }
    __syncthreads();

    // ---- MLP head on h2(23) (waves 0,1) ----
    if (wave < 2) {
      uint4 hflo = *(const uint4*)(h2s[0] + offA);
      uint4 hfhi = *(const uint4*)(h2s[0] + offA + 64);
      f32x4 am;
      #pragma unroll
      for (int r = 0; r < 4; ++r) am[r] = b1vv;
      am = mfma16(hflo, wM[0], am);
      am = mfma16(hfhi, wM[1], am);
      float yp[4];
      #pragma unroll
      for (int r = 0; r < 4; ++r) yp[r] = fmaxf(am[r], 0.0f) * w2v;
      #pragma unroll
      for (int mask = 1; mask <= 8; mask <<= 1) {
        #pragma unroll
        for (int r = 0; r < 4; ++r) yp[r] += __shfl_xor(yp[r], mask);
      }
      if (cc == 0) {
        #pragma unroll
        for (int r = 0; r < 4; ++r) pm[wave][hi * 4 + r] = yp[r];
      }
    }
    __syncthreads();

    if (wave == 0 && lane < 16) {
      float y = pm[0][lane] + pm[1][lane] + b2v;
      float pd = (s == 0) ? y : fmaf(y, 1.0f - alpha, prevp * (alpha * 0.5f));
      prevp = pd;
      win[(s % 24) * 16 + lane] = pd;
      out[(long)(b0g + lane) * nsteps + s] = pd;
    }
    __syncthreads();
  } // s
}

extern "C" void kernel_launch(void* const* d_in, const int* in_sizes, int n_in,
                              void* d_out, int out_size, void* d_ws, size_t ws_size,
                              hipStream_t stream) {
  (void)in_sizes; (void)n_in; (void)out_size; (void)d_ws; (void)ws_size;
  lstm_forecast<<<NBLK, NTHR, 0, stream>>>(
      (const float*)d_in[0],
      (const float*)d_in[1],  (const float*)d_in[2],
      (const float*)d_in[3],  (const float*)d_in[4],
      (const float*)d_in[5],  (const float*)d_in[6],
      (const float*)d_in[7],  (const float*)d_in[8],
      (const float*)d_in[9],  (const float*)d_in[10],
      (const float*)d_in[11], (const float*)d_in[12],
      (const float*)d_in[13], (const int*)d_in[14],
      (float*)d_out);
}

// Round 14
// 633.420 us; speedup vs baseline: 1.1245x; 1.1245x over previous
//
#include <hip/hip_runtime.h>

// AutoregressiveForecaster R14: dual-step software pipeline (steps s and s+1
// overlapped with 12-iter skew) on the R9 base. 2-layer LSTM(H=64) + MLP,
// 20 steps, 24-window, B=8192.
//
//  - 512 blocks x 256 threads (4 waves), one 16-batch M-tile per block,
//    2 blocks/CU (launch_bounds(256,2)).
//  - DEPENDENCY: step s+1's window differs from known data only in slot s%24
//    (= pred(s)), first read at its iter 22. So step s (iters 12..23) and
//    step s+1 (iters 0..11) run in the same barrier intervals: 21 blocks x 12
//    intervals ~= 252 barriers total vs R9's 540, each with 2x independent
//    work (48 MFMA + 16 gatesteps, two disjoint chains) -> amortizes the
//    ~900cy/interval fixed drain that R9 couldn't hide.
//  - Contexts ctx[s&1]: separate h1/h2 double-buffers + c-state (c regs only;
//    A-frags reloaded per interval -> no cross-interval frag state).
//  - Folds: MLP(b-1) at t=0, blend+window-write at t=1 (write of pred(b-1)
//    precedes step b's read of it at t=10 for L0(23)), prologue(b+2) at t=11
//    (writes ctx[b&1].h1[0]; dying step b writes h2[0] only - no alias).
//  - Fused-7 gates (R9-verified; R13's Pade regressed - issue-bound, not
//    trans-bound). Weights pre-scaled by log2e (2x g-gate), frags in VGPRs.

typedef _Float16 f16x8 __attribute__((ext_vector_type(8)));
typedef float f32x4 __attribute__((ext_vector_type(4)));

#define NBLK 512
#define NTHR 256
#define SRB  144   // h row stride bytes

__device__ __forceinline__ float rcp_(float x) { return __builtin_amdgcn_rcpf(x); }
__device__ __forceinline__ float exp2_(float x) { return __builtin_amdgcn_exp2f(x); }
__device__ __forceinline__ f32x4 mfma16(uint4 a, uint4 b, f32x4 c) {
  return __builtin_amdgcn_mfma_f32_16x16x32_f16(
      __builtin_bit_cast(f16x8, a), __builtin_bit_cast(f16x8, b), c, 0, 0, 0);
}
__device__ __forceinline__ uint4 pack8s(const float* p, float s) {
  union { uint4 u; _Float16 h[8]; } r;
  #pragma unroll
  for (int i = 0; i < 8; ++i) r.h[i] = (_Float16)(p[i] * s);
  return r.u;
}
// fused LSTM gate update; pre-activations pre-scaled by log2e (2x for g-gate).
__device__ __forceinline__ float gatestep(float aI, float aF, float aG, float aO,
                                          float& cst) {
  float xx = exp2_(-aI), xf = exp2_(-aF), yy = exp2_(-aG), xo = exp2_(-aO);
  float P = (1.0f + xx) * (1.0f + yy);
  float Q = 1.0f + xf;
  float N = fmaf(cst, P, (1.0f - yy) * Q);   // c*P + (1-yy)*Q
  float cv = N * rcp_(P * Q);
  cst = cv;
  float z = exp2_(-2.88539008178f * cv);
  return (1.0f - z) * rcp_((1.0f + xo) * (1.0f + z));
}

__global__ __launch_bounds__(NTHR, 2) void lstm_forecast(
    const float* __restrict__ x,
    const float* __restrict__ Wih0, const float* __restrict__ Whh0,
    const float* __restrict__ bih0, const float* __restrict__ bhh0,
    const float* __restrict__ Wih1, const float* __restrict__ Whh1,
    const float* __restrict__ bih1, const float* __restrict__ bhh1,
    const float* __restrict__ W1,   const float* __restrict__ b1,
    const float* __restrict__ W2,   const float* __restrict__ b2,
    const float* __restrict__ damping, const int* __restrict__ stepsPtr,
    float* __restrict__ out)
{
  __shared__ __align__(16) char h1s[2][2][16 * SRB];   // [ctx][parity]
  __shared__ __align__(16) char h2s[2][2][16 * SRB];
  __shared__ __align__(16) float win[24 * 16];
  __shared__ __align__(16) float pm[2][16];

  const int tid  = threadIdx.x;
  const int wave = tid >> 6;
  const int lane = tid & 63;
  const int cc   = lane & 15;
  const int hi   = lane >> 4;
  const int b0g  = blockIdx.x * 16;
  const float L2E = 1.44269504089f;

  // ---- weight B-fragments into VGPRs (pre-scaled; gt: 0=i,1=f,2=g,3=o) ----
  uint4 wB0[4][2], wB1[4][2], wB2[4][2];
  float bias0v[4], wih0v[4];
  f32x4 bi1[4];
  #pragma unroll
  for (int gt = 0; gt < 4; ++gt) {
    float sc = (gt == 2) ? 2.0f * L2E : L2E;
    int row = (wave + 4 * gt) * 16 + cc;
    #pragma unroll
    for (int f = 0; f < 2; ++f) {
      int col = f * 32 + hi * 8;
      wB0[gt][f] = pack8s(Whh0 + row * 64 + col, sc);
      wB1[gt][f] = pack8s(Wih1 + row * 64 + col, sc);
      wB2[gt][f] = pack8s(Whh1 + row * 64 + col, sc);
    }
    bias0v[gt] = (bih0[row] + bhh0[row]) * sc;
    wih0v[gt]  = Wih0[row] * sc;
    float b1c  = (bih1[row] + bhh1[row]) * sc;
    #pragma unroll
    for (int r = 0; r < 4; ++r) bi1[gt][r] = b1c;
  }
  uint4 wM[2];
  {
    int row = (wave & 1) * 16 + cc;
    wM[0] = pack8s(W1 + row * 64 + hi * 8, 1.0f);
    wM[1] = pack8s(W1 + row * 64 + 32 + hi * 8, 1.0f);
  }
  const float w2v  = W2[(wave & 1) * 16 + cc];
  const float b1vv = b1[(wave & 1) * 16 + cc];
  const float alpha  = rcp_(1.0f + exp2_(-L2E * damping[0]));
  const int   nsteps = stepsPtr[0];
  const float b2v    = b2[0];

  for (int e = tid; e < 384; e += NTHR) {
    int b = e & 15, t = e >> 4;
    win[t * 16 + b] = x[(b0g + b) * 24 + t];
  }

  const int offA = cc * SRB + hi * 16;
  const int offS = (wave * 16 + cc) * 2;
  float prevp = 0.0f;
  float cX1[4], cX2[4], cY1[4], cY2[4];

  // L0(0) of step s2, h1(-1)=0: elementwise only; writes h1ctx[0], inits c1.
  auto prologue = [&](int s2, char* h1c0, float* c1) {
    int ph = s2; if (ph >= 24) ph -= 24;
    float4 xw = *(const float4*)&win[ph * 16 + hi * 4];
    float xa[4] = {xw.x, xw.y, xw.z, xw.w};
    #pragma unroll
    for (int r = 0; r < 4; ++r) {
      c1[r] = 0.0f;
      float hv = gatestep(fmaf(xa[r], wih0v[0], bias0v[0]),
                          fmaf(xa[r], wih0v[1], bias0v[1]),
                          fmaf(xa[r], wih0v[2], bias0v[2]),
                          fmaf(xa[r], wih0v[3], bias0v[3]), c1[r]);
      *(_Float16*)(h1c0 + (hi * 4 + r) * SRB + offS) = (_Float16)hv;
    }
  };

  // iter `it` of step s: L1(it) [+ L0(it+1) unless last]; frags loaded here.
  auto core = [&](int s, int it, char* h1c0, char* h1c1, char* h2c0, char* h2c1,
                  float* c1, float* c2, bool last) {
    const bool rp = (it & 1) != 0;
    char* h1r = rp ? h1c1 : h1c0;
    char* h2r = rp ? h2c1 : h2c0;
    char* h1w = rp ? h1c0 : h1c1;
    char* h2w = rp ? h2c0 : h2c1;
    uint4 a1lo = *(const uint4*)(h1r + offA);
    uint4 a1hi = *(const uint4*)(h1r + offA + 64);
    uint4 a2lo, a2hi;
    if (it == 0) {
      a2lo = make_uint4(0, 0, 0, 0); a2hi = a2lo;
    } else {
      a2lo = *(const uint4*)(h2r + offA);
      a2hi = *(const uint4*)(h2r + offA + 64);
    }
    f32x4 acc1[4];
    #pragma unroll
    for (int gt = 0; gt < 4; ++gt) {
      f32x4 tv = mfma16(a1lo, wB1[gt][0], bi1[gt]);
      tv = mfma16(a1hi, wB1[gt][1], tv);
      tv = mfma16(a2lo, wB2[gt][0], tv);
      acc1[gt] = mfma16(a2hi, wB2[gt][1], tv);
    }
    if (!last) {
      int ph = s + it + 1; if (ph >= 24) ph -= 24;
      float4 xw = *(const float4*)&win[ph * 16 + hi * 4];
      float xa[4] = {xw.x, xw.y, xw.z, xw.w};
      f32x4 acc0[4];
      #pragma unroll
      for (int gt = 0; gt < 4; ++gt) {
        f32x4 ai;
        #pragma unroll
        for (int r = 0; r < 4; ++r) ai[r] = fmaf(xa[r], wih0v[gt], bias0v[gt]);
        f32x4 tv = mfma16(a1lo, wB0[gt][0], ai);
        acc0[gt] = mfma16(a1hi, wB0[gt][1], tv);
      }
      #pragma unroll
      for (int r = 0; r < 4; ++r) {
        float hv = gatestep(acc1[0][r], acc1[1][r], acc1[2][r], acc1[3][r], c2[r]);
        *(_Float16*)(h2w + (hi * 4 + r) * SRB + offS) = (_Float16)hv;
      }
      #pragma unroll
      for (int r = 0; r < 4; ++r) {
        float hv = gatestep(acc0[0][r], acc0[1][r], acc0[2][r], acc0[3][r], c1[r]);
        *(_Float16*)(h1w + (hi * 4 + r) * SRB + offS) = (_Float16)hv;
      }
    } else {
      #pragma unroll
      for (int r = 0; r < 4; ++r) {
        float hv = gatestep(acc1[0][r], acc1[1][r], acc1[2][r], acc1[3][r], c2[r]);
        *(_Float16*)(h2w + (hi * 4 + r) * SRB + offS) = (_Float16)hv;
      }
    }
  };

  // MLP on a final h2 (parity-0 buffer of the given ctx); waves 0,1.
  auto mlp = [&](char* h2c0) {
    if (wave < 2) {
      uint4 hflo = *(const uint4*)(h2c0 + offA);
      uint4 hfhi = *(const uint4*)(h2c0 + offA + 64);
      f32x4 am;
      #pragma unroll
      for (int r = 0; r < 4; ++r) am[r] = b1vv;
      am = mfma16(hflo, wM[0], am);
      am = mfma16(hfhi, wM[1], am);
      float yp[4];
      #pragma unroll
      for (int r = 0; r < 4; ++r) yp[r] = fmaxf(am[r], 0.0f) * w2v;
      #pragma unroll
      for (int mask = 1; mask <= 8; mask <<= 1) {
        #pragma unroll
        for (int r = 0; r < 4; ++r) yp[r] += __shfl_xor(yp[r], mask);
      }
      if (cc == 0) {
        #pragma unroll
        for (int r = 0; r < 4; ++r) pm[wave][hi * 4 + r] = yp[r];
      }
    }
  };

  auto blend = [&](int sPred, bool writeWin) {
    if (wave == 0 && lane < 16) {
      float y = pm[0][lane] + pm[1][lane] + b2v;
      float pd = (sPred == 0) ? y : fmaf(y, 1.0f - alpha, prevp * (alpha * 0.5f));
      prevp = pd;
      if (writeWin) {
        int slot = sPred; if (slot >= 24) slot -= 24;
        win[slot * 16 + lane] = pd;
      }
      out[(long)(b0g + lane) * nsteps + sPred] = pd;
    }
  };

  // block b: step b iters 12..23 (chain A) || step b+1 iters 0..11 (chain B)
  auto blockBody = [&](int b,
                       float* c1A, float* c2A, char* h1A0, char* h1A1,
                       char* h2A0, char* h2A1,
                       float* c1B, float* c2B, char* h1B0, char* h1B1,
                       char* h2B0, char* h2B1) {
    const bool hasA = (b >= 0);
    const bool hasB = (b + 1 < nsteps);
    for (int t = 0; t < 12; ++t) {
      if (hasA) core(b, t + 12, h1A0, h1A1, h2A0, h2A1, c1A, c2A, t == 11);
      if (hasB) core(b + 1, t, h1B0, h1B1, h2B0, h2B1, c1B, c2B, false);
      if (t == 0 && b >= 1) mlp(h2B0);   // ctx[(b-1)&1] == B's ctx
      if (t == 1 && b >= 1) blend(b - 1, true);
      if (t == 11 && b + 2 < nsteps) {
        prologue(b + 2, h1A0, c1A);      // ctx[(b+2)&1] == A's ctx
        #pragma unroll
        for (int r = 0; r < 4; ++r) c2A[r] = 0.0f;
      }
      __syncthreads();
    }
  };

  // ---- pre-loop: prologue(0) into ctx0 ----
  prologue(0, h1s[0][0], cX1);
  #pragma unroll
  for (int r = 0; r < 4; ++r) cX2[r] = 0.0f;
  __syncthreads();

  for (int b = -1; b < nsteps; ++b) {
    if ((b & 1) == 0)
      blockBody(b, cX1, cX2, h1s[0][0], h1s[0][1], h2s[0][0], h2s[0][1],
                   cY1, cY2, h1s[1][0], h1s[1][1], h2s[1][0], h2s[1][1]);
    else
      blockBody(b, cY1, cY2, h1s[1][0], h1s[1][1], h2s[1][0], h2s[1][1],
                   cX1, cX2, h1s[0][0], h1s[0][1], h2s[0][0], h2s[0][1]);
  }

  // ---- tail: MLP + blend for the final step ----
  mlp(h2s[(nsteps - 1) & 1][0]);
  __syncthreads();
  blend(nsteps - 1, false);
}

extern "C" void kernel_launch(void* const* d_in, const int* in_sizes, int n_in,
                              void* d_out, int out_size, void* d_ws, size_t ws_size,
                              hipStream_t stream) {
  (void)in_sizes; (void)n_in; (void)out_size; (void)d_ws; (void)ws_size;
  lstm_forecast<<<NBLK, NTHR, 0, stream>>>(
      (const float*)d_in[0],
      (const float*)d_in[1],  (const float*)d_in[2],
      (const float*)d_in[3],  (const float*)d_in[4],
      (const float*)d_in[5],  (const float*)d_in[6],
      (const float*)d_in[7],  (const float*)d_in[8],
      (const float*)d_in[9],  (const float*)d_in[10],
      (const float*)d_in[11], (const float*)d_in[12],
      (const float*)d_in[13], (const int*)d_in[14],
      (float*)d_out);
}